// Round 4
// baseline (486.714 us; speedup 1.0000x reference)
//
#include <hip/hip_runtime.h>
#include <hip/hip_bf16.h>

// TAGConv K=2, D=128. Round 4:
//  - GEMM: W staged in LDS (96 KB, fragment-swizzled, fp32->bf16 in-staging),
//    512-thread persistent blocks, grid-stride over 128-row tiles. B frags via
//    conflict-free ds_read_b128 instead of per-wave global loads.
//  - SpMM: unroll 4 (16 gathers in flight per wave).

#define D 128
#define TPB 256
#define TPG 512
#define GEMM_GRID 256

typedef __attribute__((ext_vector_type(8))) short short8;
typedef __attribute__((ext_vector_type(4))) float f32x4;

__device__ __forceinline__ ushort f2bf(float f) {
    unsigned u = __float_as_uint(f);
    u += 0x7fff + ((u >> 16) & 1);      // round-to-nearest-even
    return (ushort)(u >> 16);
}
__device__ __forceinline__ unsigned pack2bf(float x, float y) {
    return (unsigned)f2bf(x) | ((unsigned)f2bf(y) << 16);
}
__device__ __forceinline__ float bf_lo(unsigned v) { return __uint_as_float(v << 16); }
__device__ __forceinline__ float bf_hi(unsigned v) { return __uint_as_float(v & 0xffff0000u); }

// ---------------- degree ----------------
__global__ void deg_kernel(const int* __restrict__ dst, int* __restrict__ deg, int e) {
    int i = blockIdx.x * TPB + threadIdx.x;
    if (i < e) atomicAdd(&deg[dst[i]], 1);
}

// ---------------- exclusive scan over deg ----------------
__global__ void scan1_kernel(const int* __restrict__ deg, int* __restrict__ rs,
                             int* __restrict__ bsum, int n) {
    __shared__ int s[TPB];
    int t = threadIdx.x;
    int i = blockIdx.x * TPB + t;
    int v = (i < n) ? deg[i] : 0;
    s[t] = v;
    __syncthreads();
    for (int off = 1; off < TPB; off <<= 1) {
        int x = (t >= off) ? s[t - off] : 0;
        __syncthreads();
        s[t] += x;
        __syncthreads();
    }
    if (i < n) rs[i] = s[t] - v;
    if (t == TPB - 1) bsum[blockIdx.x] = s[t];
}

__global__ void scan2_kernel(int* __restrict__ bsum, int nb) {
    __shared__ int s[512];
    int t = threadIdx.x;
    int v = (t < nb) ? bsum[t] : 0;
    s[t] = v;
    __syncthreads();
    for (int off = 1; off < 512; off <<= 1) {
        int x = (t >= off) ? s[t - off] : 0;
        __syncthreads();
        s[t] += x;
        __syncthreads();
    }
    if (t < nb) bsum[t] = s[t] - v;
}

__global__ void finalize_kernel(int* __restrict__ rs, const int* __restrict__ bsum,
                                const int* __restrict__ deg, float* __restrict__ norm,
                                int n, int e_total) {
    int i = blockIdx.x * TPB + threadIdx.x;
    if (i < n) {
        rs[i] += bsum[blockIdx.x];
        norm[i] = rsqrtf((float)deg[i]);
    }
    if (i == n) rs[n] = e_total;
}

// ---------------- CSR scatter ----------------
__global__ void scatter_kernel(const int* __restrict__ src, const int* __restrict__ dst,
                               const int* __restrict__ rs, int* __restrict__ cursor,
                               int* __restrict__ csr, int e) {
    int i = blockIdx.x * TPB + threadIdx.x;
    if (i < e) {
        int v = dst[i];
        int pos = rs[v] + atomicAdd(&cursor[v], 1);
        csr[pos] = src[i];
    }
}

// ---------------- prescale: featb = bf16(feat) ----------------
__global__ __launch_bounds__(TPB) void prescale_kernel(
    const float* __restrict__ feat, unsigned* __restrict__ featb, int n) {
    int gid = blockIdx.x * TPB + threadIdx.x;
    int node = gid >> 6, c = gid & 63;
    if (node >= n) return;
    float2 f = ((const float2*)(feat + (size_t)node * D))[c];
    featb[(size_t)node * 64 + c] = pack2bf(f.x, f.y);
}

// ---------------- SpMM: hout[v] = bf16( norm[v] * sum_u norm[u]*hin[u] ) ----
// One wave per dst node; quarter-wave q handles edge beg+j*4+q, c = lane&15
// handles a 16B column chunk. 1 KB per gather instruction; unroll 4.
__global__ __launch_bounds__(TPB) void spmm_kernel(
    const unsigned* __restrict__ hin, const int* __restrict__ rs,
    const int* __restrict__ csr, const float* __restrict__ norm,
    unsigned* __restrict__ hout, int n) {
    int w = (blockIdx.x * TPB + threadIdx.x) >> 6;
    if (w >= n) return;
    int lane = threadIdx.x & 63;
    int q = lane >> 4;
    int c = lane & 15;
    int beg = rs[w], end = rs[w + 1];
    float acc[8] = {};
#pragma unroll 4
    for (int j = beg + q; j < end; j += 4) {
        int u = csr[j];                    // broadcast within quarter-wave
        float s = norm[u];                 // L2-resident 400KB table
        uint4 v = *(const uint4*)(hin + (size_t)u * 64 + c * 4);
        acc[0] = fmaf(s, bf_lo(v.x), acc[0]);
        acc[1] = fmaf(s, bf_hi(v.x), acc[1]);
        acc[2] = fmaf(s, bf_lo(v.y), acc[2]);
        acc[3] = fmaf(s, bf_hi(v.y), acc[3]);
        acc[4] = fmaf(s, bf_lo(v.z), acc[4]);
        acc[5] = fmaf(s, bf_hi(v.z), acc[5]);
        acc[6] = fmaf(s, bf_lo(v.w), acc[6]);
        acc[7] = fmaf(s, bf_hi(v.w), acc[7]);
    }
#pragma unroll
    for (int k = 0; k < 8; ++k) {
        acc[k] += __shfl_xor(acc[k], 16, 64);
        acc[k] += __shfl_xor(acc[k], 32, 64);
    }
    if (q == 0) {
        float nv = norm[w];
        uint4 r;
        r.x = pack2bf(acc[0] * nv, acc[1] * nv);
        r.y = pack2bf(acc[2] * nv, acc[3] * nv);
        r.z = pack2bf(acc[4] * nv, acc[5] * nv);
        r.w = pack2bf(acc[6] * nv, acc[7] * nv);
        *(uint4*)(hout + (size_t)w * 64 + c * 4) = r;
    }
}

// ---------------- GEMM: out[n][128] = [featb|h1b|h2b] @ W^T + b ----------------
// 512 thr = 8 waves, 96 KB LDS holds all of W as bf16 MFMA fragments.
// Fragment frag=(ks*8+t): lane (q*16+m) holds W[col=t*16+m][k=ks*32+q*8 .. +7].
// Grid-stride over 128-row tiles; wave w owns rows tile*128 + w*16 .. +15.
// A frag: m=lane&15 row, k=(lane>>4)*8+j.  C/D: col=lane&15, row=(lane>>4)*4+reg.
__global__ __launch_bounds__(TPG, 2) void gemm_mfma_kernel(
    const ushort* __restrict__ featb, const ushort* __restrict__ h1b,
    const ushort* __restrict__ h2b, const float* __restrict__ W,
    const float* __restrict__ bias, float* __restrict__ out, int n, int ntiles) {
    __shared__ short8 Wl[12 * 8 * 64];       // 6144 frags-slots * 16 B = 96 KB
    int tid = threadIdx.x;

    // stage + convert: 6144 16B-chunks, 12 per thread
#pragma unroll
    for (int i = 0; i < 12; ++i) {
        int id = tid + TPG * i;              // 0..6143
        int ncol = id / 48;                  // W row (output col), 48 chunks/row
        int c = id % 48;                     // 16B bf16 chunk = 8 k-elements
        int ks = c >> 2, q = c & 3;
        const float* wp = W + (size_t)ncol * 384 + c * 8;
        float4 w0 = *(const float4*)wp;
        float4 w1 = *(const float4*)(wp + 4);
        uint4 pk;
        pk.x = pack2bf(w0.x, w0.y);
        pk.y = pack2bf(w0.z, w0.w);
        pk.z = pack2bf(w1.x, w1.y);
        pk.w = pack2bf(w1.z, w1.w);
        int frag = ks * 8 + (ncol >> 4);
        *(uint4*)&Wl[frag * 64 + q * 16 + (ncol & 15)] = pk;
    }
    __syncthreads();

    int wave = tid >> 6, lane = tid & 63;
    int m = lane & 15, q = lane >> 4;
    const ushort* srcs[3] = {featb, h1b, h2b};

    for (int tile = blockIdx.x; tile < ntiles; tile += gridDim.x) {
        int row_a = tile * 128 + wave * 16 + m;
        bool va = row_a < n;
        size_t arow = (size_t)row_a * D;
        f32x4 acc[8] = {};
#pragma unroll
        for (int ks = 0; ks < 12; ++ks) {
            short8 a = {};
            if (va) a = *(const short8*)(srcs[ks >> 2] + arow + (ks & 3) * 32 + q * 8);
#pragma unroll
            for (int t = 0; t < 8; ++t) {
                short8 b = Wl[(ks * 8 + t) * 64 + lane];
                acc[t] = __builtin_amdgcn_mfma_f32_16x16x32_bf16(a, b, acc[t], 0, 0, 0);
            }
        }
        int row_c0 = tile * 128 + wave * 16 + q * 4;
#pragma unroll
        for (int t = 0; t < 8; ++t) {
            int col = t * 16 + m;
            float bv = bias[col];
#pragma unroll
            for (int r = 0; r < 4; ++r) {
                int row = row_c0 + r;
                if (row < n) out[(size_t)row * D + col] = acc[t][r] + bv;
            }
        }
    }
}

extern "C" void kernel_launch(void* const* d_in, const int* in_sizes, int n_in,
                              void* d_out, int out_size, void* d_ws, size_t ws_size,
                              hipStream_t stream) {
    const float* feat = (const float*)d_in[0];
    const int* src    = (const int*)d_in[1];
    const int* dst    = (const int*)d_in[2];
    const float* W    = (const float*)d_in[3];
    const float* bias = (const float*)d_in[4];
    float* out        = (float*)d_out;

    const int N = in_sizes[0] / D;     // 100000
    const int E = in_sizes[1];         // 1600000

    char* ws = (char*)d_ws;
    size_t off = 0;
    auto bump = [&](size_t bytes) {
        char* p = ws + off;
        off += (bytes + 255) & ~(size_t)255;
        return p;
    };
    int* deg        = (int*)bump((size_t)N * 4);       // zeroed below (adjacent w/ cursor)
    int* cursor     = (int*)bump((size_t)N * 4);       // zeroed below
    float* norm     = (float*)bump((size_t)N * 4);
    int* rs         = (int*)bump((size_t)(N + 1) * 4);
    int* bsum       = (int*)bump(512 * 4);
    int* csr        = (int*)bump((size_t)E * 4);
    unsigned* featb = (unsigned*)bump((size_t)N * 64 * 4);   // bf16x2 rows
    unsigned* h1b   = (unsigned*)bump((size_t)N * 64 * 4);
    unsigned* h2b   = (unsigned*)bump((size_t)N * 64 * 4);
    (void)ws_size;

    const int nb_n  = (N + TPB - 1) / TPB;
    const int nb_e  = (E + TPB - 1) / TPB;
    const int nb_n1 = (N + 1 + TPB - 1) / TPB;

    // zero deg + cursor (adjacent allocations)
    hipMemsetAsync(deg, 0, (((size_t)N * 4 + 255) & ~(size_t)255) + (size_t)N * 4, stream);

    deg_kernel<<<nb_e, TPB, 0, stream>>>(dst, deg, E);
    scan1_kernel<<<nb_n, TPB, 0, stream>>>(deg, rs, bsum, N);
    scan2_kernel<<<1, 512, 0, stream>>>(bsum, nb_n);
    finalize_kernel<<<nb_n1, TPB, 0, stream>>>(rs, bsum, deg, norm, N, E);
    scatter_kernel<<<nb_e, TPB, 0, stream>>>(src, dst, rs, cursor, csr, E);

    const int pres_blocks = (N * 64 + TPB - 1) / TPB;
    prescale_kernel<<<pres_blocks, TPB, 0, stream>>>(feat, featb, N);

    const int spmm_blocks = (N * 64 + TPB - 1) / TPB;  // 1 wave per node
    spmm_kernel<<<spmm_blocks, TPB, 0, stream>>>(featb, rs, csr, norm, h1b, N);
    spmm_kernel<<<spmm_blocks, TPB, 0, stream>>>(h1b, rs, csr, norm, h2b, N);

    const int ntiles = (N + 127) / 128;                // 782
    gemm_mfma_kernel<<<GEMM_GRID, TPG, 0, stream>>>(
        (const ushort*)featb, (const ushort*)h1b, (const ushort*)h2b,
        W, bias, out, N, ntiles);
}

// Round 5
// 431.417 us; speedup vs baseline: 1.1282x; 1.1282x over previous
//
#include <hip/hip_runtime.h>
#include <hip/hip_bf16.h>

// TAGConv K=2, D=128. Round 5:
//  - GEMM: W held in REGISTERS (each wave owns a 32-col slice = 24 bf16 frags
//    = 96 VGPR, loaded once per block). No LDS. Grid-stride over 16-row
//    microtiles; 4 waves share the same A rows (L1-served). Small per-XCD
//    footprint -> no L2 thrash (round-4 lesson: 96KB LDS tiles inflated
//    FETCH 2.5x / WRITE 3x via partial-line eviction RMW).
//  - scatter: cursor via atomicSub on deg (deletes cursor array).

#define D 128
#define TPB 256
#define GEMM_GRID 768

typedef __attribute__((ext_vector_type(8))) short short8;
typedef __attribute__((ext_vector_type(4))) float f32x4;

__device__ __forceinline__ ushort f2bf(float f) {
    unsigned u = __float_as_uint(f);
    u += 0x7fff + ((u >> 16) & 1);      // round-to-nearest-even
    return (ushort)(u >> 16);
}
__device__ __forceinline__ unsigned pack2bf(float x, float y) {
    return (unsigned)f2bf(x) | ((unsigned)f2bf(y) << 16);
}
__device__ __forceinline__ float bf_lo(unsigned v) { return __uint_as_float(v << 16); }
__device__ __forceinline__ float bf_hi(unsigned v) { return __uint_as_float(v & 0xffff0000u); }

// ---------------- degree ----------------
__global__ void deg_kernel(const int* __restrict__ dst, int* __restrict__ deg, int e) {
    int i = blockIdx.x * TPB + threadIdx.x;
    if (i < e) atomicAdd(&deg[dst[i]], 1);
}

// ---------------- exclusive scan over deg ----------------
__global__ void scan1_kernel(const int* __restrict__ deg, int* __restrict__ rs,
                             int* __restrict__ bsum, int n) {
    __shared__ int s[TPB];
    int t = threadIdx.x;
    int i = blockIdx.x * TPB + t;
    int v = (i < n) ? deg[i] : 0;
    s[t] = v;
    __syncthreads();
    for (int off = 1; off < TPB; off <<= 1) {
        int x = (t >= off) ? s[t - off] : 0;
        __syncthreads();
        s[t] += x;
        __syncthreads();
    }
    if (i < n) rs[i] = s[t] - v;
    if (t == TPB - 1) bsum[blockIdx.x] = s[t];
}

__global__ void scan2_kernel(int* __restrict__ bsum, int nb) {
    __shared__ int s[512];
    int t = threadIdx.x;
    int v = (t < nb) ? bsum[t] : 0;
    s[t] = v;
    __syncthreads();
    for (int off = 1; off < 512; off <<= 1) {
        int x = (t >= off) ? s[t - off] : 0;
        __syncthreads();
        s[t] += x;
        __syncthreads();
    }
    if (t < nb) bsum[t] = s[t] - v;
}

__global__ void finalize_kernel(int* __restrict__ rs, const int* __restrict__ bsum,
                                const int* __restrict__ deg, float* __restrict__ norm,
                                int n, int e_total) {
    int i = blockIdx.x * TPB + threadIdx.x;
    if (i < n) {
        rs[i] += bsum[blockIdx.x];
        norm[i] = rsqrtf((float)deg[i]);
    }
    if (i == n) rs[n] = e_total;
}

// ---------------- CSR scatter: cursor = countdown on deg ----------------
__global__ void scatter_kernel(const int* __restrict__ src, const int* __restrict__ dst,
                               const int* __restrict__ rs, int* __restrict__ deg,
                               int* __restrict__ csr, int e) {
    int i = blockIdx.x * TPB + threadIdx.x;
    if (i < e) {
        int v = dst[i];
        int pos = rs[v] + atomicSub(&deg[v], 1) - 1;
        csr[pos] = src[i];
    }
}

// ---------------- prescale: featb = bf16(feat) ----------------
__global__ __launch_bounds__(TPB) void prescale_kernel(
    const float* __restrict__ feat, unsigned* __restrict__ featb, int n) {
    int gid = blockIdx.x * TPB + threadIdx.x;
    int node = gid >> 6, c = gid & 63;
    if (node >= n) return;
    float2 f = ((const float2*)(feat + (size_t)node * D))[c];
    featb[(size_t)node * 64 + c] = pack2bf(f.x, f.y);
}

// ---------------- W -> bf16 ----------------
__global__ void wconv_kernel(const float* __restrict__ W, ushort* __restrict__ Wb, int n) {
    int i = blockIdx.x * TPB + threadIdx.x;
    if (i < n) Wb[i] = f2bf(W[i]);
}

// ---------------- SpMM: hout[v] = bf16( norm[v] * sum_u norm[u]*hin[u] ) ----
__global__ __launch_bounds__(TPB) void spmm_kernel(
    const unsigned* __restrict__ hin, const int* __restrict__ rs,
    const int* __restrict__ csr, const float* __restrict__ norm,
    unsigned* __restrict__ hout, int n) {
    int w = (blockIdx.x * TPB + threadIdx.x) >> 6;
    if (w >= n) return;
    int lane = threadIdx.x & 63;
    int q = lane >> 4;
    int c = lane & 15;
    int beg = rs[w], end = rs[w + 1];
    float acc[8] = {};
#pragma unroll 4
    for (int j = beg + q; j < end; j += 4) {
        int u = csr[j];
        float s = norm[u];
        uint4 v = *(const uint4*)(hin + (size_t)u * 64 + c * 4);
        acc[0] = fmaf(s, bf_lo(v.x), acc[0]);
        acc[1] = fmaf(s, bf_hi(v.x), acc[1]);
        acc[2] = fmaf(s, bf_lo(v.y), acc[2]);
        acc[3] = fmaf(s, bf_hi(v.y), acc[3]);
        acc[4] = fmaf(s, bf_lo(v.z), acc[4]);
        acc[5] = fmaf(s, bf_hi(v.z), acc[5]);
        acc[6] = fmaf(s, bf_lo(v.w), acc[6]);
        acc[7] = fmaf(s, bf_hi(v.w), acc[7]);
    }
#pragma unroll
    for (int k = 0; k < 8; ++k) {
        acc[k] += __shfl_xor(acc[k], 16, 64);
        acc[k] += __shfl_xor(acc[k], 32, 64);
    }
    if (q == 0) {
        float nv = norm[w];
        uint4 r;
        r.x = pack2bf(acc[0] * nv, acc[1] * nv);
        r.y = pack2bf(acc[2] * nv, acc[3] * nv);
        r.z = pack2bf(acc[4] * nv, acc[5] * nv);
        r.w = pack2bf(acc[6] * nv, acc[7] * nv);
        *(uint4*)(hout + (size_t)w * 64 + c * 4) = r;
    }
}

// ---------------- GEMM: out[n][128] = [featb|h1b|h2b] @ Wb^T + b ----------------
// 256 thr = 4 waves. Wave w owns output cols [w*32, w*32+32): its 24 B-frags
// (12 ks x 2 t) live in registers, loaded once. Grid-stride over 16-row
// microtiles; all 4 waves read the same 16 A-rows (L1-served reuse).
// A frag: row m=lane&15, k=(lane>>4)*8+j.  C/D: col=lane&15, row=(lane>>4)*4+reg.
__global__ __launch_bounds__(TPB) void gemm_mfma_kernel(
    const ushort* __restrict__ featb, const ushort* __restrict__ h1b,
    const ushort* __restrict__ h2b, const ushort* __restrict__ Wb,
    const float* __restrict__ bias, float* __restrict__ out, int n, int ntiles) {
    int lane = threadIdx.x & 63;
    int wave = threadIdx.x >> 6;
    int m = lane & 15, q = lane >> 4;

    // preload this wave's 32-col slice of W as MFMA B-fragments (96 VGPR)
    short8 b[12][2];
#pragma unroll
    for (int ks = 0; ks < 12; ++ks)
#pragma unroll
        for (int t = 0; t < 2; ++t)
            b[ks][t] = *(const short8*)(Wb + (size_t)(wave * 32 + t * 16 + m) * 384
                                        + ks * 32 + q * 8);
    float bv0 = bias[wave * 32 + m];
    float bv1 = bias[wave * 32 + 16 + m];

    const ushort* srcs[3] = {featb, h1b, h2b};

    for (int tile = blockIdx.x; tile < ntiles; tile += gridDim.x) {
        int row = tile * 16 + m;
        bool va = row < n;
        size_t arow = (size_t)row * D;
        short8 a[12] = {};
        if (va) {
#pragma unroll
            for (int ks = 0; ks < 12; ++ks)
                a[ks] = *(const short8*)(srcs[ks >> 2] + arow + (ks & 3) * 32 + q * 8);
        }
        f32x4 acc0 = {}, acc1 = {};
#pragma unroll
        for (int ks = 0; ks < 12; ++ks) {
            acc0 = __builtin_amdgcn_mfma_f32_16x16x32_bf16(a[ks], b[ks][0], acc0, 0, 0, 0);
            acc1 = __builtin_amdgcn_mfma_f32_16x16x32_bf16(a[ks], b[ks][1], acc1, 0, 0, 0);
        }
        int r0 = tile * 16 + q * 4;
#pragma unroll
        for (int r = 0; r < 4; ++r) {
            int rw = r0 + r;
            if (rw < n) {
                size_t o = (size_t)rw * D + wave * 32 + m;
                out[o] = acc0[r] + bv0;
                out[o + 16] = acc1[r] + bv1;
            }
        }
    }
}

extern "C" void kernel_launch(void* const* d_in, const int* in_sizes, int n_in,
                              void* d_out, int out_size, void* d_ws, size_t ws_size,
                              hipStream_t stream) {
    const float* feat = (const float*)d_in[0];
    const int* src    = (const int*)d_in[1];
    const int* dst    = (const int*)d_in[2];
    const float* W    = (const float*)d_in[3];
    const float* bias = (const float*)d_in[4];
    float* out        = (float*)d_out;

    const int N = in_sizes[0] / D;     // 100000
    const int E = in_sizes[1];         // 1600000

    char* ws = (char*)d_ws;
    size_t off = 0;
    auto bump = [&](size_t bytes) {
        char* p = ws + off;
        off += (bytes + 255) & ~(size_t)255;
        return p;
    };
    int* deg        = (int*)bump((size_t)N * 4);       // zeroed below; consumed by scatter
    float* norm     = (float*)bump((size_t)N * 4);
    int* rs         = (int*)bump((size_t)(N + 1) * 4);
    int* bsum       = (int*)bump(512 * 4);
    int* csr        = (int*)bump((size_t)E * 4);
    unsigned* featb = (unsigned*)bump((size_t)N * 64 * 4);   // bf16x2 rows
    unsigned* h1b   = (unsigned*)bump((size_t)N * 64 * 4);
    unsigned* h2b   = (unsigned*)bump((size_t)N * 64 * 4);
    ushort* Wb      = (ushort*)bump((size_t)D * 384 * 2);
    (void)ws_size;

    const int nb_n  = (N + TPB - 1) / TPB;
    const int nb_e  = (E + TPB - 1) / TPB;
    const int nb_n1 = (N + 1 + TPB - 1) / TPB;

    hipMemsetAsync(deg, 0, (size_t)N * 4, stream);

    deg_kernel<<<nb_e, TPB, 0, stream>>>(dst, deg, E);
    scan1_kernel<<<nb_n, TPB, 0, stream>>>(deg, rs, bsum, N);
    scan2_kernel<<<1, 512, 0, stream>>>(bsum, nb_n);
    finalize_kernel<<<nb_n1, TPB, 0, stream>>>(rs, bsum, deg, norm, N, E);
    scatter_kernel<<<nb_e, TPB, 0, stream>>>(src, dst, rs, deg, csr, E);

    const int pres_blocks = (N * 64 + TPB - 1) / TPB;
    prescale_kernel<<<pres_blocks, TPB, 0, stream>>>(feat, featb, N);
    wconv_kernel<<<(D * 384 + TPB - 1) / TPB, TPB, 0, stream>>>(W, Wb, D * 384);

    const int spmm_blocks = (N * 64 + TPB - 1) / TPB;  // 1 wave per node
    spmm_kernel<<<spmm_blocks, TPB, 0, stream>>>(featb, rs, csr, norm, h1b, N);
    spmm_kernel<<<spmm_blocks, TPB, 0, stream>>>(h1b, rs, csr, norm, h2b, N);

    const int ntiles = (N + 15) / 16;                  // 6250
    gemm_mfma_kernel<<<GEMM_GRID, TPB, 0, stream>>>(
        (const ushort*)featb, (const ushort*)h1b, (const ushort*)h2b,
        Wb, bias, out, N, ntiles);
}

// Round 6
// 331.695 us; speedup vs baseline: 1.4674x; 1.3006x over previous
//
#include <hip/hip_runtime.h>
#include <hip/hip_bf16.h>

// TAGConv K=2, D=128. Round 6: CSR build rewritten as bucketed counting sort.
// Round-5 lesson: random 4B stores cost a full 64B HBM partial-line write each
// (scatter WRITE_SIZE was 104 MB = 1.6M x 64B at 1.3 TB/s). New build:
//   count (LDS hist) -> bucket scan -> binscatter (packed, cell-contiguous)
//   -> per-bucket LDS sort + sequential CSR dump (also emits rs & norm).
// Deletes deg/scan1/scan2/finalize/scatter and all 1.6M-global-atomic passes.
// SpMM (1KB-per-gather, quarter-wave) and register-W MFMA GEMM unchanged.

#define D 128
#define TPB 256
#define GEMM_GRID 768

#define BSH 9
#define BSZ 512              // nodes per bucket
#define NBMAX 256            // max buckets (N<=131072); TPB must equal NBMAX
#define EPT 16               // edges per thread in binscatter
#define CH (TPB * EPT)       // 4096 edges per WG
#define LCAP 16384           // per-bucket CSR slice cap (avg ~8.2K, ~90 sigma)

typedef __attribute__((ext_vector_type(8))) short short8;
typedef __attribute__((ext_vector_type(4))) float f32x4;

__device__ __forceinline__ ushort f2bf(float f) {
    unsigned u = __float_as_uint(f);
    u += 0x7fff + ((u >> 16) & 1);      // round-to-nearest-even
    return (ushort)(u >> 16);
}
__device__ __forceinline__ unsigned pack2bf(float x, float y) {
    return (unsigned)f2bf(x) | ((unsigned)f2bf(y) << 16);
}
__device__ __forceinline__ float bf_lo(unsigned v) { return __uint_as_float(v << 16); }
__device__ __forceinline__ float bf_hi(unsigned v) { return __uint_as_float(v & 0xffff0000u); }

// ---------------- build 1: bucket histogram ----------------
__global__ __launch_bounds__(TPB) void count_kernel(
    const int* __restrict__ dst, int* __restrict__ bucketCnt, int e) {
    __shared__ int hist[NBMAX];
    int t = threadIdx.x;
    hist[t] = 0;
    __syncthreads();
    int base = blockIdx.x * CH;
    int lim = base + CH < e ? base + CH : e;
    for (int i = base + t; i < lim; i += TPB)
        atomicAdd(&hist[dst[i] >> BSH], 1);
    __syncthreads();
    int h = hist[t];
    if (h) atomicAdd(&bucketCnt[t], h);
}

// ---------------- build 2: exclusive scan of bucket counts ----------------
__global__ __launch_bounds__(NBMAX) void bucket_scan_kernel(
    const int* __restrict__ bucketCnt, int* __restrict__ bucketBase, int nb, int e) {
    __shared__ int s[NBMAX];
    int t = threadIdx.x;
    int v = (t < nb) ? bucketCnt[t] : 0;
    s[t] = v;
    __syncthreads();
    for (int o = 1; o < NBMAX; o <<= 1) {
        int x = (t >= o) ? s[t - o] : 0;
        __syncthreads();
        s[t] += x;
        __syncthreads();
    }
    bucketBase[t] = s[t] - v;
    if (t == 0) bucketBase[nb] = e;
}

// ---------------- build 3: bin edges into bucket regions (packed 4B) --------
// pk = (src << 9) | (dst & 511)  (17+9 = 26 bits). Cell per (WG,bucket) is
// claimed with ONE global atomic; writes within a cell are contiguous.
__global__ __launch_bounds__(TPB) void binscatter_kernel(
    const int* __restrict__ src, const int* __restrict__ dst,
    const int* __restrict__ bucketBase, int* __restrict__ gCursor,
    unsigned* __restrict__ tmp, int e) {
    __shared__ int hist[NBMAX];
    __shared__ int cellBase[NBMAX];
    int t = threadIdx.x;
    hist[t] = 0;
    __syncthreads();
    int base = blockIdx.x * CH;
    int b[EPT]; unsigned pk[EPT]; int r[EPT];
#pragma unroll
    for (int k = 0; k < EPT; ++k) {
        int i = base + k * TPB + t;
        b[k] = -1;
        if (i < e) {
            int d = dst[i];
            b[k] = d >> BSH;
            pk[k] = ((unsigned)src[i] << BSH) | (unsigned)(d & (BSZ - 1));
            r[k] = atomicAdd(&hist[b[k]], 1);
        }
    }
    __syncthreads();
    int h = hist[t];
    cellBase[t] = h ? bucketBase[t] + atomicAdd(&gCursor[t], h) : 0;
    __syncthreads();
#pragma unroll
    for (int k = 0; k < EPT; ++k)
        if (b[k] >= 0) tmp[cellBase[b[k]] + r[k]] = pk[k];
}

// ---------------- build 4: per-bucket CSR in LDS + sequential dump ----------
// One WG per bucket. Emits csr slice (coalesced), rs[node], norm[node].
__global__ __launch_bounds__(TPB) void bucket_csr_kernel(
    const unsigned* __restrict__ tmp, const int* __restrict__ bucketBase,
    int* __restrict__ rs, float* __restrict__ norm, int* __restrict__ csr,
    int n, int e) {
    __shared__ int cnt[BSZ];
    __shared__ int off[BSZ];
    __shared__ int pr[TPB];
    __shared__ int lcsr[LCAP];
    int t = threadIdx.x;
    int bkt = blockIdx.x;
    int beg = bucketBase[bkt], end = bucketBase[bkt + 1];
    int m = end - beg;
    cnt[t] = 0; cnt[t + TPB] = 0;
    __syncthreads();
    for (int i = beg + t; i < end; i += TPB)
        atomicAdd(&cnt[tmp[i] & (BSZ - 1)], 1);
    __syncthreads();
    // exclusive scan of cnt[512] via 256-pair Hillis-Steele
    int c0 = cnt[2 * t], c1 = cnt[2 * t + 1];
    pr[t] = c0 + c1;
    int own = c0 + c1;
    __syncthreads();
    for (int o = 1; o < TPB; o <<= 1) {
        int x = (t >= o) ? pr[t - o] : 0;
        __syncthreads();
        pr[t] += x;
        __syncthreads();
    }
    int ex = pr[t] - own;
    off[2 * t] = ex;
    off[2 * t + 1] = ex + c0;
    __syncthreads();
    cnt[t] = 0; cnt[t + TPB] = 0;          // reuse as rank counters
    __syncthreads();
    for (int i = beg + t; i < end; i += TPB) {
        unsigned v = tmp[i];
        int l = v & (BSZ - 1);
        int r = atomicAdd(&cnt[l], 1);
        int idx = off[l] + r;
        if (idx < LCAP) lcsr[idx] = (int)(v >> BSH);
    }
    __syncthreads();
    int mm = m < LCAP ? m : LCAP;
    for (int i = t; i < mm; i += TPB) csr[beg + i] = lcsr[i];   // sequential
    int node0 = bkt << BSH;
    for (int l = t; l < BSZ; l += TPB) {
        int node = node0 + l;
        if (node < n) {
            rs[node] = beg + off[l];
            norm[node] = rsqrtf((float)cnt[l]);
        } else if (node == n) {
            rs[n] = e;
        }
    }
}

// ---------------- prescale: featb = bf16(feat) ----------------
__global__ __launch_bounds__(TPB) void prescale_kernel(
    const float* __restrict__ feat, unsigned* __restrict__ featb, int n) {
    int gid = blockIdx.x * TPB + threadIdx.x;
    int node = gid >> 6, c = gid & 63;
    if (node >= n) return;
    float2 f = ((const float2*)(feat + (size_t)node * D))[c];
    featb[(size_t)node * 64 + c] = pack2bf(f.x, f.y);
}

// ---------------- W -> bf16 ----------------
__global__ void wconv_kernel(const float* __restrict__ W, ushort* __restrict__ Wb, int n) {
    int i = blockIdx.x * TPB + threadIdx.x;
    if (i < n) Wb[i] = f2bf(W[i]);
}

// ---------------- SpMM: hout[v] = bf16( norm[v] * sum_u norm[u]*hin[u] ) ----
__global__ __launch_bounds__(TPB) void spmm_kernel(
    const unsigned* __restrict__ hin, const int* __restrict__ rs,
    const int* __restrict__ csr, const float* __restrict__ norm,
    unsigned* __restrict__ hout, int n) {
    int w = (blockIdx.x * TPB + threadIdx.x) >> 6;
    if (w >= n) return;
    int lane = threadIdx.x & 63;
    int q = lane >> 4;
    int c = lane & 15;
    int beg = rs[w], end = rs[w + 1];
    float acc[8] = {};
#pragma unroll 4
    for (int j = beg + q; j < end; j += 4) {
        int u = csr[j];
        float s = norm[u];
        uint4 v = *(const uint4*)(hin + (size_t)u * 64 + c * 4);
        acc[0] = fmaf(s, bf_lo(v.x), acc[0]);
        acc[1] = fmaf(s, bf_hi(v.x), acc[1]);
        acc[2] = fmaf(s, bf_lo(v.y), acc[2]);
        acc[3] = fmaf(s, bf_hi(v.y), acc[3]);
        acc[4] = fmaf(s, bf_lo(v.z), acc[4]);
        acc[5] = fmaf(s, bf_hi(v.z), acc[5]);
        acc[6] = fmaf(s, bf_lo(v.w), acc[6]);
        acc[7] = fmaf(s, bf_hi(v.w), acc[7]);
    }
#pragma unroll
    for (int k = 0; k < 8; ++k) {
        acc[k] += __shfl_xor(acc[k], 16, 64);
        acc[k] += __shfl_xor(acc[k], 32, 64);
    }
    if (q == 0) {
        float nv = norm[w];
        uint4 r;
        r.x = pack2bf(acc[0] * nv, acc[1] * nv);
        r.y = pack2bf(acc[2] * nv, acc[3] * nv);
        r.z = pack2bf(acc[4] * nv, acc[5] * nv);
        r.w = pack2bf(acc[6] * nv, acc[7] * nv);
        *(uint4*)(hout + (size_t)w * 64 + c * 4) = r;
    }
}

// ---------------- GEMM: out[n][128] = [featb|h1b|h2b] @ Wb^T + b ----------------
// 4 waves/block; wave owns a 32-col W slice in registers (24 bf16 frags).
__global__ __launch_bounds__(TPB) void gemm_mfma_kernel(
    const ushort* __restrict__ featb, const ushort* __restrict__ h1b,
    const ushort* __restrict__ h2b, const ushort* __restrict__ Wb,
    const float* __restrict__ bias, float* __restrict__ out, int n, int ntiles) {
    int lane = threadIdx.x & 63;
    int wave = threadIdx.x >> 6;
    int m = lane & 15, q = lane >> 4;

    short8 b[12][2];
#pragma unroll
    for (int ks = 0; ks < 12; ++ks)
#pragma unroll
        for (int t = 0; t < 2; ++t)
            b[ks][t] = *(const short8*)(Wb + (size_t)(wave * 32 + t * 16 + m) * 384
                                        + ks * 32 + q * 8);
    float bv0 = bias[wave * 32 + m];
    float bv1 = bias[wave * 32 + 16 + m];

    const ushort* srcs[3] = {featb, h1b, h2b};

    for (int tile = blockIdx.x; tile < ntiles; tile += gridDim.x) {
        int row = tile * 16 + m;
        bool va = row < n;
        size_t arow = (size_t)row * D;
        short8 a[12] = {};
        if (va) {
#pragma unroll
            for (int ks = 0; ks < 12; ++ks)
                a[ks] = *(const short8*)(srcs[ks >> 2] + arow + (ks & 3) * 32 + q * 8);
        }
        f32x4 acc0 = {}, acc1 = {};
#pragma unroll
        for (int ks = 0; ks < 12; ++ks) {
            acc0 = __builtin_amdgcn_mfma_f32_16x16x32_bf16(a[ks], b[ks][0], acc0, 0, 0, 0);
            acc1 = __builtin_amdgcn_mfma_f32_16x16x32_bf16(a[ks], b[ks][1], acc1, 0, 0, 0);
        }
        int r0 = tile * 16 + q * 4;
#pragma unroll
        for (int r = 0; r < 4; ++r) {
            int rw = r0 + r;
            if (rw < n) {
                size_t o = (size_t)rw * D + wave * 32 + m;
                out[o] = acc0[r] + bv0;
                out[o + 16] = acc1[r] + bv1;
            }
        }
    }
}

extern "C" void kernel_launch(void* const* d_in, const int* in_sizes, int n_in,
                              void* d_out, int out_size, void* d_ws, size_t ws_size,
                              hipStream_t stream) {
    const float* feat = (const float*)d_in[0];
    const int* src    = (const int*)d_in[1];
    const int* dst    = (const int*)d_in[2];
    const float* W    = (const float*)d_in[3];
    const float* bias = (const float*)d_in[4];
    float* out        = (float*)d_out;

    const int N = in_sizes[0] / D;     // 100000
    const int E = in_sizes[1];         // 1600000
    const int NB = (N + BSZ - 1) >> BSH;  // 196

    char* ws = (char*)d_ws;
    size_t off = 0;
    auto bump = [&](size_t bytes) {
        char* p = ws + off;
        off += (bytes + 255) & ~(size_t)255;
        return p;
    };
    int* bucketCnt   = (int*)bump((size_t)2 * NBMAX * 4);   // + gCursor, one memset
    int* gCursor     = bucketCnt + NBMAX;
    int* bucketBase  = (int*)bump((size_t)(NBMAX + 1) * 4);
    float* norm      = (float*)bump((size_t)N * 4);
    int* rs          = (int*)bump((size_t)(N + 1) * 4);
    unsigned* tmp    = (unsigned*)bump((size_t)E * 4);      // packed (src<<9|dstLow)
    int* csr         = (int*)bump((size_t)E * 4);
    unsigned* featb  = (unsigned*)bump((size_t)N * 64 * 4); // bf16x2 rows
    unsigned* h1b    = (unsigned*)bump((size_t)N * 64 * 4);
    unsigned* h2b    = (unsigned*)bump((size_t)N * 64 * 4);
    ushort* Wb       = (ushort*)bump((size_t)D * 384 * 2);
    (void)ws_size;

    hipMemsetAsync(bucketCnt, 0, (size_t)2 * NBMAX * 4, stream);

    const int nb_ch = (E + CH - 1) / CH;               // 391
    count_kernel<<<nb_ch, TPB, 0, stream>>>(dst, bucketCnt, E);
    bucket_scan_kernel<<<1, NBMAX, 0, stream>>>(bucketCnt, bucketBase, NB, E);
    binscatter_kernel<<<nb_ch, TPB, 0, stream>>>(src, dst, bucketBase, gCursor, tmp, E);
    bucket_csr_kernel<<<NB, TPB, 0, stream>>>(tmp, bucketBase, rs, norm, csr, N, E);

    const int pres_blocks = (N * 64 + TPB - 1) / TPB;
    prescale_kernel<<<pres_blocks, TPB, 0, stream>>>(feat, featb, N);
    wconv_kernel<<<(D * 384 + TPB - 1) / TPB, TPB, 0, stream>>>(W, Wb, D * 384);

    const int spmm_blocks = (N * 64 + TPB - 1) / TPB;  // 1 wave per node
    spmm_kernel<<<spmm_blocks, TPB, 0, stream>>>(featb, rs, csr, norm, h1b, N);
    spmm_kernel<<<spmm_blocks, TPB, 0, stream>>>(h1b, rs, csr, norm, h2b, N);

    const int ntiles = (N + 15) / 16;                  // 6250
    gemm_mfma_kernel<<<GEMM_GRID, TPB, 0, stream>>>(
        (const ushort*)featb, (const ushort*)h1b, (const ushort*)h2b,
        Wb, bias, out, N, ntiles);
}

// Round 7
// 308.837 us; speedup vs baseline: 1.5760x; 1.0740x over previous
//
#include <hip/hip_runtime.h>
#include <hip/hip_bf16.h>

// TAGConv K=2, D=128. Round 7: dispatch-count reduction (10 -> 6).
// Round-6 lesson: ~110 us of the 331 us is inter-dispatch overhead (~11 us
// x 10 dispatches; per-kernel work sums to only ~217 us). Changes:
//  - Fixed-capacity bucket regions (LCAP): deletes count_kernel+bucket_scan.
//    binscatter appends via gCursor; bucket_csr emits rsdeg=int2(start,deg)
//    so no global scan is needed (csr lives in bucketed layout with gaps).
//  - mega_kernel = binscatter || prescale || wconv (block-range split).
// Pipeline: memset(1KB) -> mega -> bucket_csr -> spmm1 -> spmm2 -> gemm.

#define D 128
#define TPB 256
#define GEMM_GRID 768

#define BSH 9
#define BSZ 512              // nodes per bucket
#define NBMAX 256            // max buckets
#define EPT 16               // edges per thread in binscatter
#define CH (TPB * EPT)       // 4096 edges per WG
#define LCAP 16384           // fixed per-bucket region (avg fill ~8.2K, ~90 sigma)

typedef __attribute__((ext_vector_type(8))) short short8;
typedef __attribute__((ext_vector_type(4))) float f32x4;

__device__ __forceinline__ ushort f2bf(float f) {
    unsigned u = __float_as_uint(f);
    u += 0x7fff + ((u >> 16) & 1);      // round-to-nearest-even
    return (ushort)(u >> 16);
}
__device__ __forceinline__ unsigned pack2bf(float x, float y) {
    return (unsigned)f2bf(x) | ((unsigned)f2bf(y) << 16);
}
__device__ __forceinline__ float bf_lo(unsigned v) { return __uint_as_float(v << 16); }
__device__ __forceinline__ float bf_hi(unsigned v) { return __uint_as_float(v & 0xffff0000u); }

// ---------------- mega: binscatter || prescale || wconv ----------------
// blocks [0, nbin): bin edges into fixed bucket regions (packed 4B:
//   pk = (src<<9)|(dst&511)); one global atomic per (WG,bucket).
// blocks [nbin, nbin+npre): featb = bf16(feat).
// blocks [nbin+npre, ...): Wb = bf16(W).
__global__ __launch_bounds__(TPB) void mega_kernel(
    const int* __restrict__ src, const int* __restrict__ dst,
    int* __restrict__ gCursor, unsigned* __restrict__ tmp,
    const float* __restrict__ feat, unsigned* __restrict__ featb,
    const float* __restrict__ W, ushort* __restrict__ Wb,
    int e, int n, int nbin, int npre) {
    __shared__ int hist[NBMAX];
    __shared__ int cellBase[NBMAX];
    int t = threadIdx.x;
    int bid = blockIdx.x;

    if (bid < nbin) {
        hist[t] = 0;
        __syncthreads();
        int base = bid * CH;
        int b[EPT]; unsigned pk[EPT]; int r[EPT];
#pragma unroll
        for (int k = 0; k < EPT; ++k) {
            int i = base + k * TPB + t;
            b[k] = -1;
            if (i < e) {
                int d = dst[i];
                b[k] = d >> BSH;
                pk[k] = ((unsigned)src[i] << BSH) | (unsigned)(d & (BSZ - 1));
                r[k] = atomicAdd(&hist[b[k]], 1);
            }
        }
        __syncthreads();
        int h = hist[t];
        cellBase[t] = h ? t * LCAP + atomicAdd(&gCursor[t], h) : 0;
        __syncthreads();
#pragma unroll
        for (int k = 0; k < EPT; ++k)
            if (b[k] >= 0) tmp[cellBase[b[k]] + r[k]] = pk[k];
    } else if (bid < nbin + npre) {
        int gid = (bid - nbin) * TPB + t;
        int node = gid >> 6, c = gid & 63;
        if (node >= n) return;
        float2 f = ((const float2*)(feat + (size_t)node * D))[c];
        featb[(size_t)node * 64 + c] = pack2bf(f.x, f.y);
    } else {
        int i = ((bid - nbin - npre) * TPB + t) * 4;   // D*384 = 49152 elems
        float4 w = *(const float4*)(W + i);
        ushort4 o;
        o.x = f2bf(w.x); o.y = f2bf(w.y); o.z = f2bf(w.z); o.w = f2bf(w.w);
        *(ushort4*)(Wb + i) = o;
    }
}

// ---------------- per-bucket CSR in LDS + sequential dump ----------
// One WG per bucket. Emits csr slice (coalesced, at bkt*LCAP), rsdeg, norm.
__global__ __launch_bounds__(TPB) void bucket_csr_kernel(
    const unsigned* __restrict__ tmp, const int* __restrict__ gCursor,
    int2* __restrict__ rsdeg, float* __restrict__ norm, int* __restrict__ csr,
    int n) {
    __shared__ int cnt[BSZ];
    __shared__ int off[BSZ];
    __shared__ int pr[TPB];
    __shared__ int lcsr[LCAP];
    int t = threadIdx.x;
    int bkt = blockIdx.x;
    int beg = bkt * LCAP;
    int m = gCursor[bkt];
    int end = beg + m;
    cnt[t] = 0; cnt[t + TPB] = 0;
    __syncthreads();
    for (int i = beg + t; i < end; i += TPB)
        atomicAdd(&cnt[tmp[i] & (BSZ - 1)], 1);
    __syncthreads();
    // exclusive scan of cnt[512] via 256-pair Hillis-Steele
    int c0 = cnt[2 * t], c1 = cnt[2 * t + 1];
    int own = c0 + c1;
    pr[t] = own;
    __syncthreads();
    for (int o = 1; o < TPB; o <<= 1) {
        int x = (t >= o) ? pr[t - o] : 0;
        __syncthreads();
        pr[t] += x;
        __syncthreads();
    }
    int ex = pr[t] - own;
    off[2 * t] = ex;
    off[2 * t + 1] = ex + c0;
    __syncthreads();
    cnt[t] = 0; cnt[t + TPB] = 0;          // reuse as rank counters
    __syncthreads();
    for (int i = beg + t; i < end; i += TPB) {
        unsigned v = tmp[i];
        int l = v & (BSZ - 1);
        int r = atomicAdd(&cnt[l], 1);
        int idx = off[l] + r;
        if (idx < LCAP) lcsr[idx] = (int)(v >> BSH);
    }
    __syncthreads();
    int mm = m < LCAP ? m : LCAP;
    for (int i = t; i < mm; i += TPB) csr[beg + i] = lcsr[i];   // sequential
    int node0 = bkt << BSH;
    for (int l = t; l < BSZ; l += TPB) {
        int node = node0 + l;
        if (node < n) {
            rsdeg[node] = make_int2(beg + off[l], cnt[l]);
            norm[node] = rsqrtf((float)cnt[l]);
        }
    }
}

// ---------------- SpMM: hout[v] = bf16( norm[v] * sum_u norm[u]*hin[u] ) ----
// One wave per dst node; quarter-wave q handles edge beg+j*4+q; c = lane&15
// handles a 16B column chunk. 1 KB per gather instruction; unroll 4.
__global__ __launch_bounds__(TPB) void spmm_kernel(
    const uint4* __restrict__ hin4, const int2* __restrict__ rsdeg,
    const int* __restrict__ csr, const float* __restrict__ norm,
    unsigned* __restrict__ hout, int n) {
    int w = (blockIdx.x * TPB + threadIdx.x) >> 6;
    if (w >= n) return;
    int lane = threadIdx.x & 63;
    int q = lane >> 4;
    int c = lane & 15;
    int2 rd = rsdeg[w];
    int beg = rd.x, end = rd.x + rd.y;
    float acc[8] = {};
#pragma unroll 4
    for (int j = beg + q; j < end; j += 4) {
        int u = csr[j];
        float s = norm[u];
        uint4 v = hin4[(u << 4) + c];
        acc[0] = fmaf(s, bf_lo(v.x), acc[0]);
        acc[1] = fmaf(s, bf_hi(v.x), acc[1]);
        acc[2] = fmaf(s, bf_lo(v.y), acc[2]);
        acc[3] = fmaf(s, bf_hi(v.y), acc[3]);
        acc[4] = fmaf(s, bf_lo(v.z), acc[4]);
        acc[5] = fmaf(s, bf_hi(v.z), acc[5]);
        acc[6] = fmaf(s, bf_lo(v.w), acc[6]);
        acc[7] = fmaf(s, bf_hi(v.w), acc[7]);
    }
#pragma unroll
    for (int k = 0; k < 8; ++k) {
        acc[k] += __shfl_xor(acc[k], 16, 64);
        acc[k] += __shfl_xor(acc[k], 32, 64);
    }
    if (q == 0) {
        float nv = norm[w];
        uint4 r;
        r.x = pack2bf(acc[0] * nv, acc[1] * nv);
        r.y = pack2bf(acc[2] * nv, acc[3] * nv);
        r.z = pack2bf(acc[4] * nv, acc[5] * nv);
        r.w = pack2bf(acc[6] * nv, acc[7] * nv);
        *(uint4*)(hout + (size_t)w * 64 + c * 4) = r;
    }
}

// ---------------- GEMM: out[n][128] = [featb|h1b|h2b] @ Wb^T + b ----------------
// 4 waves/block; wave owns a 32-col W slice in registers (24 bf16 frags).
// A frag: row m=lane&15, k=(lane>>4)*8+j.  C/D: col=lane&15, row=(lane>>4)*4+reg.
__global__ __launch_bounds__(TPB) void gemm_mfma_kernel(
    const ushort* __restrict__ featb, const ushort* __restrict__ h1b,
    const ushort* __restrict__ h2b, const ushort* __restrict__ Wb,
    const float* __restrict__ bias, float* __restrict__ out, int n, int ntiles) {
    int lane = threadIdx.x & 63;
    int wave = threadIdx.x >> 6;
    int m = lane & 15, q = lane >> 4;

    short8 b[12][2];
#pragma unroll
    for (int ks = 0; ks < 12; ++ks)
#pragma unroll
        for (int t = 0; t < 2; ++t)
            b[ks][t] = *(const short8*)(Wb + (size_t)(wave * 32 + t * 16 + m) * 384
                                        + ks * 32 + q * 8);
    float bv0 = bias[wave * 32 + m];
    float bv1 = bias[wave * 32 + 16 + m];

    const ushort* srcs[3] = {featb, h1b, h2b};

    for (int tile = blockIdx.x; tile < ntiles; tile += gridDim.x) {
        int row = tile * 16 + m;
        bool va = row < n;
        size_t arow = (size_t)row * D;
        short8 a[12] = {};
        if (va) {
#pragma unroll
            for (int ks = 0; ks < 12; ++ks)
                a[ks] = *(const short8*)(srcs[ks >> 2] + arow + (ks & 3) * 32 + q * 8);
        }
        f32x4 acc0 = {}, acc1 = {};
#pragma unroll
        for (int ks = 0; ks < 12; ++ks) {
            acc0 = __builtin_amdgcn_mfma_f32_16x16x32_bf16(a[ks], b[ks][0], acc0, 0, 0, 0);
            acc1 = __builtin_amdgcn_mfma_f32_16x16x32_bf16(a[ks], b[ks][1], acc1, 0, 0, 0);
        }
        int r0 = tile * 16 + q * 4;
#pragma unroll
        for (int r = 0; r < 4; ++r) {
            int rw = r0 + r;
            if (rw < n) {
                size_t o = (size_t)rw * D + wave * 32 + m;
                out[o] = acc0[r] + bv0;
                out[o + 16] = acc1[r] + bv1;
            }
        }
    }
}

extern "C" void kernel_launch(void* const* d_in, const int* in_sizes, int n_in,
                              void* d_out, int out_size, void* d_ws, size_t ws_size,
                              hipStream_t stream) {
    const float* feat = (const float*)d_in[0];
    const int* src    = (const int*)d_in[1];
    const int* dst    = (const int*)d_in[2];
    const float* W    = (const float*)d_in[3];
    const float* bias = (const float*)d_in[4];
    float* out        = (float*)d_out;

    const int N = in_sizes[0] / D;        // 100000
    const int E = in_sizes[1];            // 1600000
    const int NB = (N + BSZ - 1) >> BSH;  // 196

    char* ws = (char*)d_ws;
    size_t off = 0;
    auto bump = [&](size_t bytes) {
        char* p = ws + off;
        off += (bytes + 255) & ~(size_t)255;
        return p;
    };
    int* gCursor     = (int*)bump((size_t)NBMAX * 4);            // memset to 0
    float* norm      = (float*)bump((size_t)N * 4);
    int2* rsdeg      = (int2*)bump((size_t)N * 8);
    unsigned* tmp    = (unsigned*)bump((size_t)NB * LCAP * 4);   // 12.85 MB
    int* csr         = (int*)bump((size_t)NB * LCAP * 4);        // 12.85 MB
    unsigned* featb  = (unsigned*)bump((size_t)N * 64 * 4);      // bf16x2 rows
    unsigned* h1b    = (unsigned*)bump((size_t)N * 64 * 4);
    unsigned* h2b    = (unsigned*)bump((size_t)N * 64 * 4);
    ushort* Wb       = (ushort*)bump((size_t)D * 384 * 2);
    (void)ws_size;

    hipMemsetAsync(gCursor, 0, (size_t)NBMAX * 4, stream);

    const int nbin = (E + CH - 1) / CH;                // 391
    const int npre = (N * 64 + TPB - 1) / TPB;         // 25000
    const int nwcv = (D * 384 / 4 + TPB - 1) / TPB;    // 48
    mega_kernel<<<nbin + npre + nwcv, TPB, 0, stream>>>(
        src, dst, gCursor, tmp, feat, featb, W, Wb, E, N, nbin, npre);

    bucket_csr_kernel<<<NB, TPB, 0, stream>>>(tmp, gCursor, rsdeg, norm, csr, N);

    const int spmm_blocks = (N * 64 + TPB - 1) / TPB;  // 1 wave per node
    spmm_kernel<<<spmm_blocks, TPB, 0, stream>>>((const uint4*)featb, rsdeg, csr, norm, h1b, N);
    spmm_kernel<<<spmm_blocks, TPB, 0, stream>>>((const uint4*)h1b, rsdeg, csr, norm, h2b, N);

    const int ntiles = (N + 15) / 16;                  // 6250
    gemm_mfma_kernel<<<GEMM_GRID, TPB, 0, stream>>>(
        (const ushort*)featb, (const ushort*)h1b, (const ushort*)h2b,
        Wb, bias, out, N, ntiles);
}